// Round 16
// baseline (66.289 us; speedup 1.0000x reference)
//
#include <hip/hip_runtime.h>
#include <hip/hip_bf16.h>

// NCE / NT-Xent loss, B=4096, D=256, temp=0.5.
// loss = mean_i( log(sum_{j!=i} exp(sim_ij)) - sim_{i,(i+B)%N} ), N=8192.
// |sim| <= 2 => exp(sim) <= e^2: plain sum(exp), no online max.
//
// R16: 64 rows/wave. LDS-read pipe scales as 1/(rows per wave); at 32 it was
// ~14-20us/CU, co-equal with MFMA 16.6us. Doubling rows halves it. The A
// fragments (32 x bf16x8 = 128 VGPR) are loaded via asm volatile
// global_load_dwordx4 -- unrematerializable, so the R5-R10 "compiler reloads
// A every tile" failure mode is structurally impossible. 128-thr blocks
// (2 waves), __launch_bounds__(128,2) -> 256 VGPR budget.
// Keeps R15's proven pieces: 4-buffer rotating LDS-B, counted vmcnt (never 0
// in-loop), branch-free epilogue (diag/pos offloaded algebraically), plus
// T5 setprio around the MFMA cluster.
//
// Zn stored scaled by sqrt(2*log2(e)) so MFMA output IS the exp2 argument.
// Fragment-tiled Zn: 16-row group g, element (g*16+rr, d), ks=d>>5,
// lhi=(d>>3)&3, dlo=d&7 -> zn[g*4096 + ks*512 + lhi*128 + rr*8 + dlo];
// lane l's fragment ks of group g = 16B at zn + g*4096 + ks*512 + l*8.

constexpr int kN  = 8192;        // 2B rows
constexpr int kD  = 256;         // embedding dim
constexpr int kBH = 4096;        // B
constexpr int kChunks  = 32;     // column chunks (256 cols each)
constexpr int kColsPer = kN / kChunks;
constexpr int kNT = kColsPer / 16;        // 16 tiles per chunk
constexpr float kSqrtScale = 1.6986436f;  // sqrt(2*log2(e))
constexpr float kLn2 = 0.6931471805599453f;

typedef __attribute__((ext_vector_type(8))) short bf16x8;  // 4 VGPRs
typedef __attribute__((ext_vector_type(4))) float f32x4;

__device__ __forceinline__ unsigned short f2bf(float f) {
  union { float f; unsigned u; } x;
  x.f = f;
  unsigned u = x.u;
  return (unsigned short)((u + 0x7FFFu + ((u >> 16) & 1u)) >> 16);
}
__device__ __forceinline__ float bf2f(unsigned short h) {
  union { unsigned u; float f; } x;
  x.u = ((unsigned)h) << 16;
  return x.f;
}
__device__ __forceinline__ void gload_lds16(const short* g, short* l) {
  __builtin_amdgcn_global_load_lds(
      (const __attribute__((address_space(1))) void*)g,
      (__attribute__((address_space(3))) void*)l, 16, 0, 0);
}
// Remat-proof 16B load: asm volatile cannot be re-executed by the compiler.
__device__ __forceinline__ bf16x8 gload16(const unsigned short* p) {
  bf16x8 r;
  asm volatile("global_load_dwordx4 %0, %1, off"
               : "=v"(r) : "v"(p) : "memory");
  return r;
}

// ---------------- kernel 1: row-normalize fp32 -> bf16 (tiled + scaled) ---
// Blocks 0..7 zero s_sum; stream order guarantees completion before k_simlse.
__global__ void k_normalize(const float* __restrict__ e1,
                            const float* __restrict__ e2,
                            unsigned short* __restrict__ zn,
                            float* __restrict__ s_sum) {
  if (blockIdx.x < 8) {
    float4 z4 = {0.f, 0.f, 0.f, 0.f};
    *reinterpret_cast<float4*>(s_sum + blockIdx.x * 1024 + threadIdx.x * 4) = z4;
  }
  const int wave = threadIdx.x >> 6;
  const int lane = threadIdx.x & 63;
  const int row  = blockIdx.x * 4 + wave;
  const float* src = (row < kBH) ? (e1 + (size_t)row * kD)
                                 : (e2 + (size_t)(row - kBH) * kD);
  float4 v = *reinterpret_cast<const float4*>(src + lane * 4);
  float ssq = v.x * v.x + v.y * v.y + v.z * v.z + v.w * v.w;
#pragma unroll
  for (int m = 1; m < 64; m <<= 1) ssq += __shfl_xor(ssq, m);
  const float invs = kSqrtScale / sqrtf(ssq);   // eps can never bind (|z|~16)
  ushort4 o;
  o.x = f2bf(v.x * invs);
  o.y = f2bf(v.y * invs);
  o.z = f2bf(v.z * invs);
  o.w = f2bf(v.w * invs);
  const int g  = row >> 4;
  const int rr = row & 15;
  const size_t dst = (size_t)g * 4096 + (lane >> 3) * 512 +
                     ((lane >> 1) & 3) * 128 + rr * 8 + (lane & 1) * 4;
  *reinterpret_cast<ushort4*>(zn + dst) = o;
}

// ---------------- kernel 1b: row-pair dots (pos + diag), 1 wave/pair ------
__global__ void k_pos(const unsigned short* __restrict__ zn,
                      float* __restrict__ pos_val,
                      float* __restrict__ dacc) {
  const int wave = threadIdx.x >> 6;
  const int lane = threadIdx.x & 63;
  const int i = blockIdx.x * 4 + wave;        // 0..4095
  const int j = i + kBH;
  const int rr = i & 15;
  const size_t off = (size_t)(i >> 4) * 4096 + (lane >> 3) * 512 +
                     ((lane >> 1) & 3) * 128 + rr * 8 + (lane & 1) * 4;
  ushort4 ua = *reinterpret_cast<const ushort4*>(zn + off);
  ushort4 ub = *reinterpret_cast<const ushort4*>(zn + off + (size_t)256 * 4096);
  float dij = 0.f, dii = 0.f, djj = 0.f;
  const unsigned short* pa = &ua.x;
  const unsigned short* pb = &ub.x;
#pragma unroll
  for (int q = 0; q < 4; ++q) {
    const float a = bf2f(pa[q]);
    const float b = bf2f(pb[q]);
    dij += a * b;
    dii += a * a;
    djj += b * b;
  }
#pragma unroll
  for (int m = 1; m < 64; m <<= 1) {
    dij += __shfl_xor(dij, m);
    dii += __shfl_xor(dii, m);
    djj += __shfl_xor(djj, m);
  }
  if (lane == 0) {
    const float p = dij * kLn2;   // scaled-dot * ln2 == sim/temp
    pos_val[i] = p;
    pos_val[j] = p;
    dacc[i] = dii;
    dacc[j] = djj;
  }
}

// ---------------- kernel 2: GEMM + exp + row-sum, LDS-B pipeline ----------
// Grid: 64 row-tiles (128 rows) x 32 col-chunks (256 cols) = 2048 blocks.
// Block: 2 waves x 64 rows. Per tile (16 cols x 256d = 8KB in LDS):
// barrier; stage(t+3); vmcnt(12); barrier; 8 ds_read -> 32 MFMA -> 16 exp2.
__global__ __launch_bounds__(128, 2)
void k_simlse(const unsigned short* __restrict__ zn,
              float* __restrict__ s_sum) {
  __shared__ __align__(16) short ldsB[4][4096];   // 4 rotating 8KB tiles

  const int bid = blockIdx.x;
  const int rt  = bid >> 5;   // row tile 0..63
  const int ch  = bid & 31;   // column chunk 0..31 (fast -> XCD L2 spread)
  const int tid = threadIdx.x;
  const int wave = tid >> 6;
  const int lane = tid & 63;
  const int l15 = lane & 15;
  const int lhi = lane >> 4;
  const int rowBase = rt * 128 + wave * 64;   // wave's 64 rows
  const int grpBase = ch * kNT;               // first 16-col group of chunk

  // ---- A fragments: 4 groups x 8 ks = 32 x bf16x8 = 128 VGPR, asm-pinned --
  bf16x8 a[4][8];
  {
    const unsigned short* ap = zn + (size_t)(rowBase >> 4) * 4096 + lane * 8;
#pragma unroll
    for (int g = 0; g < 4; ++g)
#pragma unroll
      for (int ks = 0; ks < 8; ++ks)
        a[g][ks] = gload16(ap + g * 4096 + ks * 512);
  }

  // Stage tile (t&15) into buffer (t&3); 128 threads x 4 x 16B = 8KB.
  auto stage = [&](int t) {
    const short* src = (const short*)zn +
                       (size_t)(grpBase + (t & (kNT - 1))) * 4096;
    short* dst = &ldsB[t & 3][0];
#pragma unroll
    for (int r = 0; r < 4; ++r)
      gload_lds16(src + r * 1024 + tid * 8, dst + r * 1024 + tid * 8);
  };

  stage(0);
  stage(1);
  stage(2);
  // Drain A-loads AND prologue stages: exact in-loop vmcnt counting.
  asm volatile("s_waitcnt vmcnt(0)" ::: "memory");

  float sacc[4][4];
#pragma unroll
  for (int g = 0; g < 4; ++g)
#pragma unroll
    for (int j = 0; j < 4; ++j) sacc[g][j] = 0.f;

#pragma unroll 1
  for (int t = 0; t < kNT; ++t) {
    __builtin_amdgcn_s_barrier();   // A: all waves done reading tile t-1
    stage(t + 3);                   // overwrites tile t-1's buffer (safe)
    asm volatile("s_waitcnt vmcnt(12)" ::: "memory");  // tile t resident
    __builtin_amdgcn_s_barrier();   // B: visible to both waves

    const short* bt = &ldsB[t & 3][0];
    bf16x8 b[8];
#pragma unroll
    for (int ks = 0; ks < 8; ++ks)
      b[ks] = *reinterpret_cast<const bf16x8*>(bt + ks * 512 + lane * 8);

    f32x4 acc[4];
#pragma unroll
    for (int g = 0; g < 4; ++g) acc[g] = {0.f, 0.f, 0.f, 0.f};
    __builtin_amdgcn_s_setprio(1);
#pragma unroll
    for (int ks = 0; ks < 8; ++ks) {
      const bf16x8 bk = b[ks];
#pragma unroll
      for (int g = 0; g < 4; ++g)
        acc[g] = __builtin_amdgcn_mfma_f32_16x16x32_bf16(a[g][ks], bk, acc[g], 0, 0, 0);
    }
    __builtin_amdgcn_s_setprio(0);

    // branch-free epilogue: 16 exp2 + 16 add (diag/pos handled elsewhere)
#pragma unroll
    for (int g = 0; g < 4; ++g)
#pragma unroll
      for (int j = 0; j < 4; ++j)
        sacc[g][j] += exp2f(acc[g][j]);
  }

  // ---- fold across the 16-lane column group; l15==0 lanes own rows ----
#pragma unroll
  for (int g = 0; g < 4; ++g) {
#pragma unroll
    for (int j = 0; j < 4; ++j) {
      float sv = sacc[g][j];
#pragma unroll
      for (int m = 1; m < 16; m <<= 1) sv += __shfl_xor(sv, m);
      if (l15 == 0) {
        const int row = rowBase + g * 16 + lhi * 4 + j;
        atomicAdd(&s_sum[row], sv);
      }
    }
  }
}

// ---------------- kernel 3: log(S - diag) - pos, final reduce -------------
__global__ void k_final(const float* __restrict__ s_sum,
                        const float* __restrict__ dacc,
                        const float* __restrict__ pos_val,
                        float* __restrict__ out) {
  __shared__ float red[16];
  float acc = 0.0f;
  for (int r = threadIdx.x; r < kN; r += 1024)
    acc += logf(s_sum[r] - exp2f(dacc[r])) - pos_val[r];
#pragma unroll
  for (int m = 1; m < 64; m <<= 1) acc += __shfl_xor(acc, m);
  const int wave = threadIdx.x >> 6;
  const int lane = threadIdx.x & 63;
  if (lane == 0) red[wave] = acc;
  __syncthreads();
  if (threadIdx.x == 0) {
    float t = 0.0f;
#pragma unroll
    for (int w = 0; w < 16; ++w) t += red[w];
    out[0] = t / (float)kN;
  }
}

extern "C" void kernel_launch(void* const* d_in, const int* in_sizes, int n_in,
                              void* d_out, int out_size, void* d_ws, size_t ws_size,
                              hipStream_t stream) {
  const float* e1 = (const float*)d_in[0];
  const float* e2 = (const float*)d_in[1];
  float* out = (float*)d_out;

  // ws: [zn 4MB][s_sum 32KB][dacc 32KB][pos_val 32KB]
  unsigned short* zn = (unsigned short*)d_ws;
  float* s_sum   = (float*)((char*)d_ws + (size_t)kN * kD * 2);
  float* dacc    = s_sum + kN;
  float* pos_val = dacc + kN;

  hipLaunchKernelGGL(k_normalize, dim3(kN / 4), dim3(256), 0, stream,
                     e1, e2, zn, s_sum);
  hipLaunchKernelGGL(k_pos, dim3(kBH / 4), dim3(256), 0, stream,
                     zn, pos_val, dacc);
  hipLaunchKernelGGL(k_simlse, dim3(64 * kChunks), dim3(128), 0, stream,
                     zn, s_sum);
  hipLaunchKernelGGL(k_final, dim3(1), dim3(1024), 0, stream,
                     s_sum, dacc, pos_val, out);
}

// Round 17
// 57.734 us; speedup vs baseline: 1.1482x; 1.1482x over previous
//
#include <hip/hip_runtime.h>
#include <hip/hip_bf16.h>

// NCE / NT-Xent loss, B=4096, D=256, temp=0.5.
// loss = mean_i( log(sum_{j!=i} exp(sim_ij)) - sim_{i,(i+B)%N} ), N=8192.
// |sim| <= 2 => exp(sim) <= e^2: plain sum(exp), no online max.
//
// R17 = R15 (best, 46us) with ONE change: single barrier per tile.
//   R15 paid 2 barriers/tile (A: protect overwrite target; B: tile ready).
//   Barrier A is redundant when stage(t+3) is issued AFTER the per-tile
//   barrier: all waves arriving at barrier(t) have finished reading tile
//   t-1, whose buffer stage(t+3) overwrites. Loop becomes
//     vmcnt(4); s_barrier; stage(t+3); ds_read+MFMA+exp(t)
//   with vmcnt never drained to 0 in-loop (T4).
// Algebraic offload (R14): diag stays in row sums, k_final subtracts
//   exp2(||zhat||^2 scaled); pos computed by k_pos as row-pair dots.
//
// Zn stored scaled by sqrt(2*log2(e)) so MFMA output IS the exp2 argument.
// Fragment-tiled Zn: 16-row group g, element (g*16+rr, d), ks=d>>5,
// lhi=(d>>3)&3, dlo=d&7 -> zn[g*4096 + ks*512 + lhi*128 + rr*8 + dlo];
// lane l's fragment ks of group g = 16B at zn + g*4096 + ks*512 + l*8.

constexpr int kN  = 8192;        // 2B rows
constexpr int kD  = 256;         // embedding dim
constexpr int kBH = 4096;        // B
constexpr int kChunks  = 32;     // column chunks (256 cols each)
constexpr int kColsPer = kN / kChunks;
constexpr int kNT = kColsPer / 16;        // 16 tiles per chunk
constexpr float kSqrtScale = 1.6986436f;  // sqrt(2*log2(e))
constexpr float kLn2 = 0.6931471805599453f;

typedef __attribute__((ext_vector_type(8))) short bf16x8;  // 4 VGPRs
typedef __attribute__((ext_vector_type(4))) float f32x4;

__device__ __forceinline__ unsigned short f2bf(float f) {
  union { float f; unsigned u; } x;
  x.f = f;
  unsigned u = x.u;
  return (unsigned short)((u + 0x7FFFu + ((u >> 16) & 1u)) >> 16);
}
__device__ __forceinline__ float bf2f(unsigned short h) {
  union { unsigned u; float f; } x;
  x.u = ((unsigned)h) << 16;
  return x.f;
}
__device__ __forceinline__ void gload_lds16(const short* g, short* l) {
  __builtin_amdgcn_global_load_lds(
      (const __attribute__((address_space(1))) void*)g,
      (__attribute__((address_space(3))) void*)l, 16, 0, 0);
}

// ---------------- kernel 1: row-normalize fp32 -> bf16 (tiled + scaled) ---
// Blocks 0..7 zero s_sum; stream order guarantees completion before k_simlse.
__global__ void k_normalize(const float* __restrict__ e1,
                            const float* __restrict__ e2,
                            unsigned short* __restrict__ zn,
                            float* __restrict__ s_sum) {
  if (blockIdx.x < 8) {
    float4 z4 = {0.f, 0.f, 0.f, 0.f};
    *reinterpret_cast<float4*>(s_sum + blockIdx.x * 1024 + threadIdx.x * 4) = z4;
  }
  const int wave = threadIdx.x >> 6;
  const int lane = threadIdx.x & 63;
  const int row  = blockIdx.x * 4 + wave;
  const float* src = (row < kBH) ? (e1 + (size_t)row * kD)
                                 : (e2 + (size_t)(row - kBH) * kD);
  float4 v = *reinterpret_cast<const float4*>(src + lane * 4);
  float ssq = v.x * v.x + v.y * v.y + v.z * v.z + v.w * v.w;
#pragma unroll
  for (int m = 1; m < 64; m <<= 1) ssq += __shfl_xor(ssq, m);
  const float invs = kSqrtScale / sqrtf(ssq);   // eps can never bind (|z|~16)
  ushort4 o;
  o.x = f2bf(v.x * invs);
  o.y = f2bf(v.y * invs);
  o.z = f2bf(v.z * invs);
  o.w = f2bf(v.w * invs);
  const int g  = row >> 4;
  const int rr = row & 15;
  const size_t dst = (size_t)g * 4096 + (lane >> 3) * 512 +
                     ((lane >> 1) & 3) * 128 + rr * 8 + (lane & 1) * 4;
  *reinterpret_cast<ushort4*>(zn + dst) = o;
}

// ---------------- kernel 1b: row-pair dots (pos + diag), 1 wave/pair ------
__global__ void k_pos(const unsigned short* __restrict__ zn,
                      float* __restrict__ pos_val,
                      float* __restrict__ dacc) {
  const int wave = threadIdx.x >> 6;
  const int lane = threadIdx.x & 63;
  const int i = blockIdx.x * 4 + wave;        // 0..4095
  const int j = i + kBH;
  const int rr = i & 15;
  const size_t off = (size_t)(i >> 4) * 4096 + (lane >> 3) * 512 +
                     ((lane >> 1) & 3) * 128 + rr * 8 + (lane & 1) * 4;
  ushort4 ua = *reinterpret_cast<const ushort4*>(zn + off);
  ushort4 ub = *reinterpret_cast<const ushort4*>(zn + off + (size_t)256 * 4096);
  float dij = 0.f, dii = 0.f, djj = 0.f;
  const unsigned short* pa = &ua.x;
  const unsigned short* pb = &ub.x;
#pragma unroll
  for (int q = 0; q < 4; ++q) {
    const float a = bf2f(pa[q]);
    const float b = bf2f(pb[q]);
    dij += a * b;
    dii += a * a;
    djj += b * b;
  }
#pragma unroll
  for (int m = 1; m < 64; m <<= 1) {
    dij += __shfl_xor(dij, m);
    dii += __shfl_xor(dii, m);
    djj += __shfl_xor(djj, m);
  }
  if (lane == 0) {
    const float p = dij * kLn2;   // scaled-dot * ln2 == sim/temp
    pos_val[i] = p;
    pos_val[j] = p;
    dacc[i] = dii;
    dacc[j] = djj;
  }
}

// ---------------- kernel 2: GEMM + exp + row-sum, LDS-B pipeline ----------
// Grid: 64 row-tiles (128 rows) x 32 col-chunks (256 cols) = 2048 blocks.
// Block: 4 waves x 32 rows. Per tile (16 cols x 256d = 8KB, shared by all
// 4 waves from LDS): vmcnt(4); barrier; stage(t+3); read+MFMA+exp.
__global__ __launch_bounds__(256, 4)
void k_simlse(const unsigned short* __restrict__ zn,
              float* __restrict__ s_sum) {
  __shared__ __align__(16) short ldsB[4][4096];   // 4 rotating 8KB tiles

  const int bid = blockIdx.x;
  const int rt  = bid >> 5;   // row tile 0..63
  const int ch  = bid & 31;   // column chunk 0..31 (fast -> XCD L2 spread)
  const int wave = threadIdx.x >> 6;
  const int lane = threadIdx.x & 63;
  const int l15 = lane & 15;
  const int lhi = lane >> 4;
  const int rowBase = rt * 128 + wave * 32;
  const int grpBase = ch * kNT;   // first 16-col group of this chunk

  // ---- A fragments (2 groups = 32 rows) ----
  bf16x8 a0[8], a1[8];
  {
    const unsigned short* ap = zn + (size_t)(rowBase >> 4) * 4096 + lane * 8;
#pragma unroll
    for (int ks = 0; ks < 8; ++ks) {
      a0[ks] = *reinterpret_cast<const bf16x8*>(ap + ks * 512);
      a1[ks] = *reinterpret_cast<const bf16x8*>(ap + 4096 + ks * 512);
    }
  }

  // Stage tile (t&15) into buffer (t&3); each wave copies its 2KB slice.
  auto stage = [&](int t) {
    const short* src = (const short*)zn +
                       (size_t)(grpBase + (t & (kNT - 1))) * 4096 + wave * 1024;
    short* dst = &ldsB[t & 3][wave * 1024];
    gload_lds16(src + lane * 8, dst);
    gload_lds16(src + 512 + lane * 8, dst + 512);
  };

  stage(0);
  stage(1);
  stage(2);
  // Drain A-loads AND prologue stages: exact in-loop vmcnt counting.
  asm volatile("s_waitcnt vmcnt(0)" ::: "memory");

  float sacc[2][4] = {{0.f,0.f,0.f,0.f},{0.f,0.f,0.f,0.f}};

#pragma unroll 1
  for (int t = 0; t < kNT; ++t) {
    // Tile t resident when <=4 stage-loads outstanding (tiles t+1, t+2).
    asm volatile("s_waitcnt vmcnt(4)" ::: "memory");
    __builtin_amdgcn_s_barrier();   // single sync: tile t visible to all
                                    // waves AND all waves done with t-1
    stage(t + 3);                   // overwrites tile t-1's buffer (safe:
                                    // issued after the barrier)

    const short* bt = &ldsB[t & 3][0];
    bf16x8 b[8];
#pragma unroll
    for (int ks = 0; ks < 8; ++ks)
      b[ks] = *reinterpret_cast<const bf16x8*>(bt + ks * 512 + lane * 8);

    f32x4 acc0 = {0.f,0.f,0.f,0.f};
    f32x4 acc1 = {0.f,0.f,0.f,0.f};
    __builtin_amdgcn_s_setprio(1);
#pragma unroll
    for (int ks = 0; ks < 8; ++ks) {
      acc0 = __builtin_amdgcn_mfma_f32_16x16x32_bf16(a0[ks], b[ks], acc0, 0, 0, 0);
      acc1 = __builtin_amdgcn_mfma_f32_16x16x32_bf16(a1[ks], b[ks], acc1, 0, 0, 0);
    }
    __builtin_amdgcn_s_setprio(0);
    // branch-free epilogue: 8 exp2 + 8 add (diag/pos handled elsewhere)
#pragma unroll
    for (int j = 0; j < 4; ++j) {
      sacc[0][j] += exp2f(acc0[j]);
      sacc[1][j] += exp2f(acc1[j]);
    }
  }

  // ---- fold across the 16-lane column group; l15==0 lanes own rows ----
#pragma unroll
  for (int s = 0; s < 2; ++s) {
#pragma unroll
    for (int j = 0; j < 4; ++j) {
      float sv = sacc[s][j];
#pragma unroll
      for (int m = 1; m < 16; m <<= 1) sv += __shfl_xor(sv, m);
      if (l15 == 0) {
        const int row = rowBase + s * 16 + lhi * 4 + j;
        atomicAdd(&s_sum[row], sv);
      }
    }
  }
}

// ---------------- kernel 3: log(S - diag) - pos, final reduce -------------
__global__ void k_final(const float* __restrict__ s_sum,
                        const float* __restrict__ dacc,
                        const float* __restrict__ pos_val,
                        float* __restrict__ out) {
  __shared__ float red[16];
  float acc = 0.0f;
  for (int r = threadIdx.x; r < kN; r += 1024)
    acc += logf(s_sum[r] - exp2f(dacc[r])) - pos_val[r];
#pragma unroll
  for (int m = 1; m < 64; m <<= 1) acc += __shfl_xor(acc, m);
  const int wave = threadIdx.x >> 6;
  const int lane = threadIdx.x & 63;
  if (lane == 0) red[wave] = acc;
  __syncthreads();
  if (threadIdx.x == 0) {
    float t = 0.0f;
#pragma unroll
    for (int w = 0; w < 16; ++w) t += red[w];
    out[0] = t / (float)kN;
  }
}

extern "C" void kernel_launch(void* const* d_in, const int* in_sizes, int n_in,
                              void* d_out, int out_size, void* d_ws, size_t ws_size,
                              hipStream_t stream) {
  const float* e1 = (const float*)d_in[0];
  const float* e2 = (const float*)d_in[1];
  float* out = (float*)d_out;

  // ws: [zn 4MB][s_sum 32KB][dacc 32KB][pos_val 32KB]
  unsigned short* zn = (unsigned short*)d_ws;
  float* s_sum   = (float*)((char*)d_ws + (size_t)kN * kD * 2);
  float* dacc    = s_sum + kN;
  float* pos_val = dacc + kN;

  hipLaunchKernelGGL(k_normalize, dim3(kN / 4), dim3(256), 0, stream,
                     e1, e2, zn, s_sum);
  hipLaunchKernelGGL(k_pos, dim3(kBH / 4), dim3(256), 0, stream,
                     zn, pos_val, dacc);
  hipLaunchKernelGGL(k_simlse, dim3(64 * kChunks), dim3(256), 0, stream,
                     zn, s_sum);
  hipLaunchKernelGGL(k_final, dim3(1), dim3(1024), 0, stream,
                     s_sum, dacc, pos_val, out);
}

// Round 18
// 53.098 us; speedup vs baseline: 1.2484x; 1.0873x over previous
//
#include <hip/hip_runtime.h>
#include <hip/hip_bf16.h>

// NCE / NT-Xent loss, B=4096, D=256, temp=0.5.
// loss = mean_i( log(sum_{j!=i} exp(sim_ij)) - sim_{i,(i+B)%N} ), N=8192.
// |sim| <= 2 => exp(sim) <= e^2: plain sum(exp), no online max.
//
// R18: SYMMETRY — sim is symmetric, so only the upper-triangle tiles are
// computed (2080 of 4096 128x128 blocks). Off-diagonal blocks fold each
// exp value into BOTH the row sums (row axis) and, via sim_ij = sim_ji,
// the row sums of the column range (column axis, folded through LDS).
// Diagonal blocks fold rows only. ~51% of R17's MFMA/LDS/exp work.
// Loop structure = R17 (best): 4-buffer rotating LDS-B, single barrier
// per tile, counted vmcnt (never 0 in-loop), branch-free epilogue.
// Algebraic offload (R14): diag stays in row sums, k_final subtracts
// exp2(||zhat||^2 scaled); pos computed by k_pos as row-pair dots.
//
// Zn stored scaled by sqrt(2*log2(e)) so MFMA output IS the exp2 argument.
// Fragment-tiled Zn: 16-row group g, element (g*16+rr, d), ks=d>>5,
// lhi=(d>>3)&3, dlo=d&7 -> zn[g*4096 + ks*512 + lhi*128 + rr*8 + dlo];
// lane l's fragment ks of group g = 16B at zn + g*4096 + ks*512 + l*8.

constexpr int kN  = 8192;        // 2B rows
constexpr int kD  = 256;         // embedding dim
constexpr int kBH = 4096;        // B
constexpr int kTile = 128;       // block tile: 128x128
constexpr int kNT = kTile / 16;  // 8 column sub-tiles per block
constexpr int kGrid = 64 * 32 + 32;  // triangular grid: 2080 blocks
constexpr float kSqrtScale = 1.6986436f;  // sqrt(2*log2(e))
constexpr float kLn2 = 0.6931471805599453f;

typedef __attribute__((ext_vector_type(8))) short bf16x8;  // 4 VGPRs
typedef __attribute__((ext_vector_type(4))) float f32x4;

__device__ __forceinline__ unsigned short f2bf(float f) {
  union { float f; unsigned u; } x;
  x.f = f;
  unsigned u = x.u;
  return (unsigned short)((u + 0x7FFFu + ((u >> 16) & 1u)) >> 16);
}
__device__ __forceinline__ float bf2f(unsigned short h) {
  union { unsigned u; float f; } x;
  x.u = ((unsigned)h) << 16;
  return x.f;
}
__device__ __forceinline__ void gload_lds16(const short* g, short* l) {
  __builtin_amdgcn_global_load_lds(
      (const __attribute__((address_space(1))) void*)g,
      (__attribute__((address_space(3))) void*)l, 16, 0, 0);
}

// ---------------- kernel 1: row-normalize fp32 -> bf16 (tiled + scaled) ---
// Blocks 0..7 zero s_sum; stream order guarantees completion before k_simlse.
__global__ void k_normalize(const float* __restrict__ e1,
                            const float* __restrict__ e2,
                            unsigned short* __restrict__ zn,
                            float* __restrict__ s_sum) {
  if (blockIdx.x < 8) {
    float4 z4 = {0.f, 0.f, 0.f, 0.f};
    *reinterpret_cast<float4*>(s_sum + blockIdx.x * 1024 + threadIdx.x * 4) = z4;
  }
  const int wave = threadIdx.x >> 6;
  const int lane = threadIdx.x & 63;
  const int row  = blockIdx.x * 4 + wave;
  const float* src = (row < kBH) ? (e1 + (size_t)row * kD)
                                 : (e2 + (size_t)(row - kBH) * kD);
  float4 v = *reinterpret_cast<const float4*>(src + lane * 4);
  float ssq = v.x * v.x + v.y * v.y + v.z * v.z + v.w * v.w;
#pragma unroll
  for (int m = 1; m < 64; m <<= 1) ssq += __shfl_xor(ssq, m);
  const float invs = kSqrtScale / sqrtf(ssq);   // eps can never bind (|z|~16)
  ushort4 o;
  o.x = f2bf(v.x * invs);
  o.y = f2bf(v.y * invs);
  o.z = f2bf(v.z * invs);
  o.w = f2bf(v.w * invs);
  const int g  = row >> 4;
  const int rr = row & 15;
  const size_t dst = (size_t)g * 4096 + (lane >> 3) * 512 +
                     ((lane >> 1) & 3) * 128 + rr * 8 + (lane & 1) * 4;
  *reinterpret_cast<ushort4*>(zn + dst) = o;
}

// ---------------- kernel 1b: row-pair dots (pos + diag), 1 wave/pair ------
__global__ void k_pos(const unsigned short* __restrict__ zn,
                      float* __restrict__ pos_val,
                      float* __restrict__ dacc) {
  const int wave = threadIdx.x >> 6;
  const int lane = threadIdx.x & 63;
  const int i = blockIdx.x * 4 + wave;        // 0..4095
  const int j = i + kBH;
  const int rr = i & 15;
  const size_t off = (size_t)(i >> 4) * 4096 + (lane >> 3) * 512 +
                     ((lane >> 1) & 3) * 128 + rr * 8 + (lane & 1) * 4;
  ushort4 ua = *reinterpret_cast<const ushort4*>(zn + off);
  ushort4 ub = *reinterpret_cast<const ushort4*>(zn + off + (size_t)256 * 4096);
  float dij = 0.f, dii = 0.f, djj = 0.f;
  const unsigned short* pa = &ua.x;
  const unsigned short* pb = &ub.x;
#pragma unroll
  for (int q = 0; q < 4; ++q) {
    const float a = bf2f(pa[q]);
    const float b = bf2f(pb[q]);
    dij += a * b;
    dii += a * a;
    djj += b * b;
  }
#pragma unroll
  for (int m = 1; m < 64; m <<= 1) {
    dij += __shfl_xor(dij, m);
    dii += __shfl_xor(dii, m);
    djj += __shfl_xor(djj, m);
  }
  if (lane == 0) {
    const float p = dij * kLn2;   // scaled-dot * ln2 == sim/temp
    pos_val[i] = p;
    pos_val[j] = p;
    dacc[i] = dii;
    dacc[j] = djj;
  }
}

// ---------------- kernel 2: triangular GEMM + exp + dual-axis fold --------
// Triangular grid (2080 blocks): bid<2048 -> rt=bid>>5, ct=(rt+(bid&31))&63
// (x=0 gives the 64 diagonal blocks); bid>=2048 -> rt=bid-2048, ct=rt+32.
// Each unordered 128x128 tile pair appears exactly once.
// Block: 4 waves x 32 rows. Per sub-tile (16 cols): vmcnt(4); barrier;
// stage(t+3); ds_read+MFMA+exp; fold rows (regs) and cols (LDS).
__global__ __launch_bounds__(256, 4)
void k_simlse(const unsigned short* __restrict__ zn,
              float* __restrict__ s_sum) {
  __shared__ __align__(16) short ldsB[4][4096];   // 4 rotating 8KB tiles
  __shared__ float ldsCol[4][kTile];              // per-wave column sums

  const int bid = blockIdx.x;
  int rt, ct;
  if (bid < 2048) {
    rt = bid >> 5;
    ct = (rt + (bid & 31)) & 63;
  } else {
    rt = bid - 2048;
    ct = rt + 32;
  }
  const bool offDiag = (rt != ct);
  const int wave = threadIdx.x >> 6;
  const int lane = threadIdx.x & 63;
  const int l15 = lane & 15;
  const int lhi = lane >> 4;
  const int rowBase = rt * kTile + wave * 32;
  const int grpBase = ct * kNT;   // first 16-col group of this col-panel

  // ---- A fragments (2 groups = 32 rows) ----
  bf16x8 a0[8], a1[8];
  {
    const unsigned short* ap = zn + (size_t)(rowBase >> 4) * 4096 + lane * 8;
#pragma unroll
    for (int ks = 0; ks < 8; ++ks) {
      a0[ks] = *reinterpret_cast<const bf16x8*>(ap + ks * 512);
      a1[ks] = *reinterpret_cast<const bf16x8*>(ap + 4096 + ks * 512);
    }
  }

  // Stage sub-tile (t&7) into buffer (t&3); each wave copies its 2KB slice.
  auto stage = [&](int t) {
    const short* src = (const short*)zn +
                       (size_t)(grpBase + (t & (kNT - 1))) * 4096 + wave * 1024;
    short* dst = &ldsB[t & 3][wave * 1024];
    gload_lds16(src + lane * 8, dst);
    gload_lds16(src + 512 + lane * 8, dst + 512);
  };

  stage(0);
  stage(1);
  stage(2);
  // Drain A-loads AND prologue stages: exact in-loop vmcnt counting.
  asm volatile("s_waitcnt vmcnt(0)" ::: "memory");

  float sacc[2][4] = {{0.f,0.f,0.f,0.f},{0.f,0.f,0.f,0.f}};

#pragma unroll 1
  for (int t = 0; t < kNT; ++t) {
    // Tile t resident when <=4 stage-loads outstanding (tiles t+1, t+2).
    asm volatile("s_waitcnt vmcnt(4)" ::: "memory");
    __builtin_amdgcn_s_barrier();   // tile t visible; all waves done with t-1
    stage(t + 3);                   // overwrites tile t-1's buffer (safe)

    const short* bt = &ldsB[t & 3][0];
    bf16x8 b[8];
#pragma unroll
    for (int ks = 0; ks < 8; ++ks)
      b[ks] = *reinterpret_cast<const bf16x8*>(bt + ks * 512 + lane * 8);

    f32x4 acc0 = {0.f,0.f,0.f,0.f};
    f32x4 acc1 = {0.f,0.f,0.f,0.f};
    __builtin_amdgcn_s_setprio(1);
#pragma unroll
    for (int ks = 0; ks < 8; ++ks) {
      acc0 = __builtin_amdgcn_mfma_f32_16x16x32_bf16(a0[ks], b[ks], acc0, 0, 0, 0);
      acc1 = __builtin_amdgcn_mfma_f32_16x16x32_bf16(a1[ks], b[ks], acc1, 0, 0, 0);
    }
    __builtin_amdgcn_s_setprio(0);

    // branch-free epilogue: 8 exp2; row fold in regs, col fold via shfl+LDS
    float p0[4], p1[4];
#pragma unroll
    for (int j = 0; j < 4; ++j) {
      p0[j] = exp2f(acc0[j]);
      p1[j] = exp2f(acc1[j]);
      sacc[0][j] += p0[j];
      sacc[1][j] += p1[j];
    }
    float cs = ((p0[0] + p0[1]) + (p0[2] + p0[3])) +
               ((p1[0] + p1[1]) + (p1[2] + p1[3]));
    cs += __shfl_xor(cs, 16);
    cs += __shfl_xor(cs, 32);          // lanes with lhi==0: col sum of 32 rows
    if (lhi == 0) ldsCol[wave][t * 16 + l15] = cs;  // each col written once
  }

  // ---- row fold across the 16-lane column group; l15==0 lanes own rows ----
#pragma unroll
  for (int s = 0; s < 2; ++s) {
#pragma unroll
    for (int j = 0; j < 4; ++j) {
      float sv = sacc[s][j];
#pragma unroll
      for (int m = 1; m < 16; m <<= 1) sv += __shfl_xor(sv, m);
      if (l15 == 0) {
        const int row = rowBase + s * 16 + lhi * 4 + j;
        atomicAdd(&s_sum[row], sv);
      }
    }
  }

  // ---- mirror fold: col sums -> row sums of the column range -------------
  if (offDiag) {
    __syncthreads();   // all waves' ldsCol written
    for (int c = threadIdx.x; c < kTile; c += 256) {
      const float v = (ldsCol[0][c] + ldsCol[1][c]) +
                      (ldsCol[2][c] + ldsCol[3][c]);
      atomicAdd(&s_sum[ct * kTile + c], v);
    }
  }
}

// ---------------- kernel 3: log(S - diag) - pos, final reduce -------------
__global__ void k_final(const float* __restrict__ s_sum,
                        const float* __restrict__ dacc,
                        const float* __restrict__ pos_val,
                        float* __restrict__ out) {
  __shared__ float red[16];
  float acc = 0.0f;
  for (int r = threadIdx.x; r < kN; r += 1024)
    acc += logf(s_sum[r] - exp2f(dacc[r])) - pos_val[r];
#pragma unroll
  for (int m = 1; m < 64; m <<= 1) acc += __shfl_xor(acc, m);
  const int wave = threadIdx.x >> 6;
  const int lane = threadIdx.x & 63;
  if (lane == 0) red[wave] = acc;
  __syncthreads();
  if (threadIdx.x == 0) {
    float t = 0.0f;
#pragma unroll
    for (int w = 0; w < 16; ++w) t += red[w];
    out[0] = t / (float)kN;
  }
}

extern "C" void kernel_launch(void* const* d_in, const int* in_sizes, int n_in,
                              void* d_out, int out_size, void* d_ws, size_t ws_size,
                              hipStream_t stream) {
  const float* e1 = (const float*)d_in[0];
  const float* e2 = (const float*)d_in[1];
  float* out = (float*)d_out;

  // ws: [zn 4MB][s_sum 32KB][dacc 32KB][pos_val 32KB]
  unsigned short* zn = (unsigned short*)d_ws;
  float* s_sum   = (float*)((char*)d_ws + (size_t)kN * kD * 2);
  float* dacc    = s_sum + kN;
  float* pos_val = dacc + kN;

  hipLaunchKernelGGL(k_normalize, dim3(kN / 4), dim3(256), 0, stream,
                     e1, e2, zn, s_sum);
  hipLaunchKernelGGL(k_pos, dim3(kBH / 4), dim3(256), 0, stream,
                     zn, pos_val, dacc);
  hipLaunchKernelGGL(k_simlse, dim3(kGrid), dim3(256), 0, stream,
                     zn, s_sum);
  hipLaunchKernelGGL(k_final, dim3(1), dim3(1024), 0, stream,
                     s_sum, dacc, pos_val, out);
}